// Round 11
// baseline (2438.488 us; speedup 1.0000x reference)
//
#include <hip/hip_runtime.h>
#include <hip/hip_bf16.h>
#include <stdint.h>

// Autoregressive LSTM decode, B=4096, H=1024, A=128, 50 steps.
// steps>=1: x==h  =>  gates = h @ (w_ih+w_hh)^T + bias.
// Fused launch: blocks 0-255 gates (256^2 8-phase); blocks 256-511 pred for
// the previous step (tail-fill). This round: c-prefetch after last in-loop
// vmcnt(0), peeled last K-tile with split cell epilogue (m0-3 overlapped with
// m4-7's MFMA phases), 8bm x 4j per-XCD swizzle.

#define B_SZ   4096
#define H_SZ   1024
#define A_SZ   128
#define NSTEP  50
#define NT     16      // gates K tiles of 64 (K = 1024)
#define NTP    8       // pred  K tiles of 128

using bf16 = __hip_bfloat16;
typedef __attribute__((ext_vector_type(8))) short bf16x8;   // 8 bf16 = 4 VGPR
typedef __attribute__((ext_vector_type(4))) float f32x4;    // MFMA C/D frag

__device__ __forceinline__ void gload_lds16(const void* g, void* l) {
    __builtin_amdgcn_global_load_lds(
        (const __attribute__((address_space(1))) unsigned int*)g,
        (__attribute__((address_space(3))) unsigned int*)l, 16, 0, 0);
}

#define FENCE() asm volatile("" ::: "memory")
#define BAR()   do { FENCE(); __builtin_amdgcn_s_barrier(); FENCE(); } while (0)
#define VMC6()  asm volatile("s_waitcnt vmcnt(6)" ::: "memory")
#define VMC5()  asm volatile("s_waitcnt vmcnt(5)" ::: "memory")
#define VMC4()  asm volatile("s_waitcnt vmcnt(4)" ::: "memory")
#define VMC0()  asm volatile("s_waitcnt vmcnt(0)" ::: "memory")
#define LGKM0() asm volatile("s_waitcnt lgkmcnt(0)" ::: "memory")

__device__ __forceinline__ float sigf(float x) {
    return 1.f / (1.f + __expf(-x));
}
__device__ __forceinline__ float tanh_(float x) {
    float e = __expf(-2.f * fabsf(x));
    float t = (1.f - e) / (1.f + e);
    return copysignf(t, x);
}

// ---------------- fused prep (one launch) ----------------

__global__ void prep_all(const float4* __restrict__ wih,
                         const float4* __restrict__ whh,
                         bf16* __restrict__ Wc, bf16* __restrict__ Wi,
                         const float4* __restrict__ enc, bf16* __restrict__ encb,
                         const float4* __restrict__ wpred, bf16* __restrict__ wpb,
                         const float* __restrict__ bih, const float* __restrict__ bhh,
                         float* __restrict__ bias) {
    const int b = blockIdx.x;
    if (b < 4096) {
        int i = b * 256 + threadIdx.x;
        float4 a = wih[i], c = whh[i];
        bf16 tc[4] = {__float2bfloat16(a.x + c.x), __float2bfloat16(a.y + c.y),
                      __float2bfloat16(a.z + c.z), __float2bfloat16(a.w + c.w)};
        bf16 ti[4] = {__float2bfloat16(a.x), __float2bfloat16(a.y),
                      __float2bfloat16(a.z), __float2bfloat16(a.w)};
        *(uint64_t*)(Wc + 4 * (size_t)i) = *(const uint64_t*)tc;
        *(uint64_t*)(Wi + 4 * (size_t)i) = *(const uint64_t*)ti;
    } else if (b < 8192) {
        int i = (b - 4096) * 256 + threadIdx.x;
        float4 a = enc[i];
        bf16 t[4] = {__float2bfloat16(a.x), __float2bfloat16(a.y),
                     __float2bfloat16(a.z), __float2bfloat16(a.w)};
        *(uint64_t*)(encb + 4 * (size_t)i) = *(const uint64_t*)t;
    } else if (b < 8320) {
        int i = (b - 8192) * 256 + threadIdx.x;
        float4 a = wpred[i];
        bf16 t[4] = {__float2bfloat16(a.x), __float2bfloat16(a.y),
                     __float2bfloat16(a.z), __float2bfloat16(a.w)};
        *(uint64_t*)(wpb + 4 * (size_t)i) = *(const uint64_t*)t;
    } else {
        int i = (b - 8320) * 256 + threadIdx.x;
        bias[i] = bih[i] + bhh[i];
    }
}

// ---------------- pred body (round-10 proven): 16 rows x 128 cols ----------------

__device__ __forceinline__ void pred_body(const bf16* __restrict__ h,
                                          const bf16* __restrict__ wp,
                                          const float* __restrict__ bp,
                                          float* __restrict__ pout,
                                          int pblk, int tid, bf16* sm) {
    bf16* const pH0 = sm;            // 16 x 128
    bf16* const pH1 = sm + 2048;
    bf16* const pP0 = sm + 4096;     // 128 x 128
    bf16* const pP1 = sm + 20480;

    const int w      = tid >> 6;
    const int lane   = tid & 63;
    const int lane15 = lane & 15;
    const int lhi    = lane >> 4;
    const int bm0    = pblk * 16;

    const int r   = tid >> 4;                               // stage row 0..31
    const int swb = ((tid & 15) * 16) ^ ((r & 7) << 4);     // pre-swizzled src
    const char* srcH = (const char*)h  + (size_t)(bm0 + (r & 15)) * 2048 + swb;
    const char* srcP = (const char*)wp + (size_t)r * 2048 + swb;

    int eoff[4];
#pragma unroll
    for (int kk = 0; kk < 4; ++kk)
        eoff[kk] = ((kk * 64 + lhi * 16) ^ ((lane15 & 7) << 4)) >> 1;

    f32x4 acc = {0.f, 0.f, 0.f, 0.f};

    auto STAGE = [&](int t) {
        bf16* dH = (t & 1) ? pH1 : pH0;
        bf16* dP = (t & 1) ? pP1 : pP0;
        if (w < 4)
            gload_lds16(srcH + (size_t)t * 256, dH + tid * 8);
#pragma unroll
        for (int q = 0; q < 4; ++q)
            gload_lds16(srcP + (size_t)q * 65536 + (size_t)t * 256, dP + q * 4096 + tid * 8);
    };

    STAGE(0);
#pragma unroll
    for (int t = 0; t < NTP; ++t) {
        if (t + 1 < NTP) {
            STAGE(t + 1);
            if (w < 4) { VMC5(); } else { VMC4(); }
        } else {
            VMC0();
        }
        BAR();
        const bf16* Hd = (t & 1) ? pH1 : pH0;
        const bf16* Pd = (t & 1) ? pP1 : pP0;
#pragma unroll
        for (int kk = 0; kk < 4; ++kk) {
            bf16x8 a = *(const bf16x8*)(Hd + lane15 * 128 + eoff[kk]);
            bf16x8 b = *(const bf16x8*)(Pd + (w * 16 + lane15) * 128 + eoff[kk]);
            acc = __builtin_amdgcn_mfma_f32_16x16x32_bf16(a, b, acc, 0, 0, 0);
        }
        BAR();
    }

    const int col = w * 16 + lane15;
    const float bpv = bp[col];
#pragma unroll
    for (int rr = 0; rr < 4; ++rr)
        pout[(size_t)(bm0 + lhi * 4 + rr) * A_SZ + col] = acc[rr] + bpv;
}

// ---------------- fused gates GEMM + LSTM cell + tail-fill pred ----------------

__global__ __launch_bounds__(512, 2)
void lstm_fused(const bf16* __restrict__ hin, const bf16* __restrict__ W,
                const float* __restrict__ bias, float* __restrict__ c,
                bf16* __restrict__ hout, int step0,
                const bf16* __restrict__ wp, const float* __restrict__ bp,
                float* __restrict__ pout) {
    __shared__ __align__(16) bf16 sm[65536];          // 128 KiB

    if (blockIdx.x >= 256) {
        if (pout) pred_body(hin, wp, bp, pout, blockIdx.x - 256, threadIdx.x, sm);
        return;
    }

    bf16* const lA0 = sm;
    bf16* const lA1 = sm + 16384;
    bf16* const lB0 = sm + 32768;
    bf16* const lB1 = sm + 49152;

    const int tid    = threadIdx.x;
    const int w      = tid >> 6;
    const int lane   = tid & 63;
    const int wr     = w >> 2;
    const int wc     = w & 3;
    const int lane15 = lane & 15;
    const int lhi    = lane >> 4;

    // 8bm x 4j rectangle per XCD (bijective: bm_idx=[b0,b5,b4,b3], j_idx=[b2,b1,b7,b6])
    const int bid    = blockIdx.x;
    const int bm_idx = ((bid & 1) << 3) | ((bid >> 3) & 7);
    const int j_idx  = (((bid >> 1) & 3) << 2) | ((bid >> 6) & 3);
    const int bm0    = bm_idx * 256;
    const int j0     = j_idx * 64;

    const int scolb = ((tid & 7) * 16) ^ (((tid >> 3) & 7) << 4);
    const char* baseA = (const char*)hin + (size_t)(bm0 + (tid >> 3)) * 2048 + scolb;
    const char* baseB = (const char*)W   + (size_t)(j0  + (tid >> 3)) * 2048 + scolb;

    const int cs0 = ((     lhi * 16) ^ ((lane & 7) << 4)) >> 1;
    const int cs1 = ((64 + lhi * 16) ^ ((lane & 7) << 4)) >> 1;
    const int rA  = (wr * 128 + lane15) * 64;
    const int rB  = (wc * 16  + lane15) * 64;

    const int jc = j0 + wc * 16 + lane15;

    f32x4 acc[8][4];
    const f32x4 z = {0.f, 0.f, 0.f, 0.f};
#pragma unroll
    for (int m = 0; m < 8; ++m)
#pragma unroll
        for (int n = 0; n < 4; ++n) acc[m][n] = z;

    auto SGA = [&](int t, int h) {
        bf16* dst = ((t & 1) ? lA1 : lA0) + h * 8192 + w * 512;
        const char* g = baseA + (size_t)(h * 128) * 2048 + (size_t)t * 128;
        gload_lds16(g, dst);
        gload_lds16(g + (size_t)64 * 2048, dst + 4096);
    };
    auto SGB = [&](int t, int h) {
        bf16* dst = ((t & 1) ? lB1 : lB0) + h * 8192 + w * 512;
        const char* g = baseB + (size_t)(h * 2) * 2097152 + (size_t)t * 128;
        gload_lds16(g, dst);
        gload_lds16(g + 2097152, dst + 4096);
    };

    // prologue: 7 half-tile stages (14 gload_lds)
    SGB(0, 0); SGB(0, 1); SGA(0, 0); SGA(0, 1);
    SGB(1, 0); SGB(1, 1); SGA(1, 0);

    VMC6();
    BAR();

    float cpre[8][4];   // c prefetch, live only across the peeled last tile

    for (int t = 0; t < NT - 1; ++t) {
        const bf16* Ad = (t & 1) ? lA1 : lA0;
        const bf16* Bd = (t & 1) ? lB1 : lB0;
        bf16x8 av[4][2], bv[4][2];

        // phase 0: m0-3 x n0-1; stage A1(t+1)
#pragma unroll
        for (int m = 0; m < 4; ++m) {
            av[m][0] = *(const bf16x8*)(Ad + rA + m * 1024 + cs0);
            av[m][1] = *(const bf16x8*)(Ad + rA + m * 1024 + cs1);
        }
#pragma unroll
        for (int n = 0; n < 2; ++n) {
            bv[n][0] = *(const bf16x8*)(Bd + rB + n * 4096 + cs0);
            bv[n][1] = *(const bf16x8*)(Bd + rB + n * 4096 + cs1);
        }
        SGA(t + 1, 1);
        BAR(); LGKM0();
        __builtin_amdgcn_s_setprio(1);
#pragma unroll
        for (int n = 0; n < 2; ++n)
#pragma unroll
            for (int m = 0; m < 4; ++m) {
                acc[m][n] = __builtin_amdgcn_mfma_f32_16x16x32_bf16(av[m][0], bv[n][0], acc[m][n], 0, 0, 0);
                acc[m][n] = __builtin_amdgcn_mfma_f32_16x16x32_bf16(av[m][1], bv[n][1], acc[m][n], 0, 0, 0);
            }
        __builtin_amdgcn_s_setprio(0);
        BAR();

        // phase 1: m0-3 x n2-3; stage B0(t+2)
#pragma unroll
        for (int n = 2; n < 4; ++n) {
            bv[n][0] = *(const bf16x8*)(Bd + rB + n * 4096 + cs0);
            bv[n][1] = *(const bf16x8*)(Bd + rB + n * 4096 + cs1);
        }
        if (t + 2 < NT) SGB(t + 2, 0);
        BAR(); LGKM0();
        __builtin_amdgcn_s_setprio(1);
#pragma unroll
        for (int n = 2; n < 4; ++n)
#pragma unroll
            for (int m = 0; m < 4; ++m) {
                acc[m][n] = __builtin_amdgcn_mfma_f32_16x16x32_bf16(av[m][0], bv[n][0], acc[m][n], 0, 0, 0);
                acc[m][n] = __builtin_amdgcn_mfma_f32_16x16x32_bf16(av[m][1], bv[n][1], acc[m][n], 0, 0, 0);
            }
        __builtin_amdgcn_s_setprio(0);
        BAR();

        // phase 2: m4-7 x n0-1; stage B1(t+2)
#pragma unroll
        for (int m = 0; m < 4; ++m) {
            av[m][0] = *(const bf16x8*)(Ad + rA + (m + 4) * 1024 + cs0);
            av[m][1] = *(const bf16x8*)(Ad + rA + (m + 4) * 1024 + cs1);
        }
        if (t + 2 < NT) SGB(t + 2, 1);
        BAR(); LGKM0();
        __builtin_amdgcn_s_setprio(1);
#pragma unroll
        for (int n = 0; n < 2; ++n)
#pragma unroll
            for (int m = 0; m < 4; ++m) {
                acc[m + 4][n] = __builtin_amdgcn_mfma_f32_16x16x32_bf16(av[m][0], bv[n][0], acc[m + 4][n], 0, 0, 0);
                acc[m + 4][n] = __builtin_amdgcn_mfma_f32_16x16x32_bf16(av[m][1], bv[n][1], acc[m + 4][n], 0, 0, 0);
            }
        __builtin_amdgcn_s_setprio(0);
        BAR();

        // phase 3: m4-7 x n2-3; stage A0(t+2)
        if (t + 2 < NT) SGA(t + 2, 0);
        BAR(); LGKM0();
        __builtin_amdgcn_s_setprio(1);
#pragma unroll
        for (int n = 2; n < 4; ++n)
#pragma unroll
            for (int m = 0; m < 4; ++m) {
                acc[m + 4][n] = __builtin_amdgcn_mfma_f32_16x16x32_bf16(av[m][0], bv[n][0], acc[m + 4][n], 0, 0, 0);
                acc[m + 4][n] = __builtin_amdgcn_mfma_f32_16x16x32_bf16(av[m][1], bv[n][1], acc[m + 4][n], 0, 0, 0);
            }
        __builtin_amdgcn_s_setprio(0);
        if (t == NT - 2) {
            VMC0();
            // c prefetch: issued after the last staging drain; only VMEM in
            // flight during the peeled tile; drained by VMC0 in the epilogue.
            if (!step0) {
#pragma unroll
                for (int m = 0; m < 8; ++m)
#pragma unroll
                    for (int r = 0; r < 4; ++r)
                        cpre[m][r] = c[(size_t)(bm0 + wr * 128 + m * 16 + lhi * 4 + r) * H_SZ + jc];
            } else {
#pragma unroll
                for (int m = 0; m < 8; ++m)
#pragma unroll
                    for (int r = 0; r < 4; ++r) cpre[m][r] = 0.f;
            }
        } else {
            VMC6();
        }
        BAR();
    }

    // ---- peeled last tile (t = NT-1, odd -> lA1/lB1), split cell epilogue
    const float bi  = bias[jc];
    const float bff = bias[H_SZ + jc];
    const float bg  = bias[2 * H_SZ + jc];
    const float bo  = bias[3 * H_SZ + jc];

    auto cell_half = [&](int mb) {   // cell for m = mb..mb+3
#pragma unroll
        for (int m = mb; m < mb + 4; ++m) {
#pragma unroll
            for (int r = 0; r < 4; ++r) {
                int row = bm0 + wr * 128 + m * 16 + lhi * 4 + r;
                size_t idx = (size_t)row * H_SZ + jc;
                float iv = acc[m][0][r] + bi;
                float fv = acc[m][1][r] + bff;
                float gv = acc[m][2][r] + bg;
                float ov = acc[m][3][r] + bo;
                float cn = sigf(fv) * cpre[m][r] + sigf(iv) * tanh_(gv);
                float hn = sigf(ov) * tanh_(cn);
                c[idx] = cn;
                hout[idx] = __float2bfloat16(hn);
            }
        }
    };

    {
        const bf16* Ad = lA1;
        const bf16* Bd = lB1;
        bf16x8 av[4][2], bv[4][2];

        // phase 0: m0-3 x n0-1
#pragma unroll
        for (int m = 0; m < 4; ++m) {
            av[m][0] = *(const bf16x8*)(Ad + rA + m * 1024 + cs0);
            av[m][1] = *(const bf16x8*)(Ad + rA + m * 1024 + cs1);
        }
#pragma unroll
        for (int n = 0; n < 2; ++n) {
            bv[n][0] = *(const bf16x8*)(Bd + rB + n * 4096 + cs0);
            bv[n][1] = *(const bf16x8*)(Bd + rB + n * 4096 + cs1);
        }
        LGKM0();
        __builtin_amdgcn_s_setprio(1);
#pragma unroll
        for (int n = 0; n < 2; ++n)
#pragma unroll
            for (int m = 0; m < 4; ++m) {
                acc[m][n] = __builtin_amdgcn_mfma_f32_16x16x32_bf16(av[m][0], bv[n][0], acc[m][n], 0, 0, 0);
                acc[m][n] = __builtin_amdgcn_mfma_f32_16x16x32_bf16(av[m][1], bv[n][1], acc[m][n], 0, 0, 0);
            }
        __builtin_amdgcn_s_setprio(0);

        // phase 1: m0-3 x n2-3
#pragma unroll
        for (int n = 2; n < 4; ++n) {
            bv[n][0] = *(const bf16x8*)(Bd + rB + n * 4096 + cs0);
            bv[n][1] = *(const bf16x8*)(Bd + rB + n * 4096 + cs1);
        }
        LGKM0();
        __builtin_amdgcn_s_setprio(1);
#pragma unroll
        for (int n = 2; n < 4; ++n)
#pragma unroll
            for (int m = 0; m < 4; ++m) {
                acc[m][n] = __builtin_amdgcn_mfma_f32_16x16x32_bf16(av[m][0], bv[n][0], acc[m][n], 0, 0, 0);
                acc[m][n] = __builtin_amdgcn_mfma_f32_16x16x32_bf16(av[m][1], bv[n][1], acc[m][n], 0, 0, 0);
            }
        __builtin_amdgcn_s_setprio(0);

        // phase 2 reads for m4-7 (issue before cell so ds_reads overlap VALU)
#pragma unroll
        for (int m = 0; m < 4; ++m) {
            av[m][0] = *(const bf16x8*)(Ad + rA + (m + 4) * 1024 + cs0);
            av[m][1] = *(const bf16x8*)(Ad + rA + (m + 4) * 1024 + cs1);
        }

        // m0-3 cell: acc[0..3] complete; overlaps other waves' phase-2/3 MFMAs
        VMC0();          // cpre loads landed
        cell_half(0);

        // phase 2+3: m4-7 x n0-3
        LGKM0();
        __builtin_amdgcn_s_setprio(1);
#pragma unroll
        for (int n = 0; n < 4; ++n)
#pragma unroll
            for (int m = 0; m < 4; ++m) {
                acc[m + 4][n] = __builtin_amdgcn_mfma_f32_16x16x32_bf16(av[m][0], bv[n][0], acc[m + 4][n], 0, 0, 0);
                acc[m + 4][n] = __builtin_amdgcn_mfma_f32_16x16x32_bf16(av[m][1], bv[n][1], acc[m + 4][n], 0, 0, 0);
            }
        __builtin_amdgcn_s_setprio(0);

        // m4-7 cell
        cell_half(4);
    }
}

// ---------------- standalone pred for the final step ----------------

__global__ __launch_bounds__(512)
void pred_tail(const bf16* __restrict__ h, const bf16* __restrict__ wp,
               const float* __restrict__ bp, float* __restrict__ out) {
    __shared__ __align__(16) bf16 sm2[36864];     // 72 KiB
    pred_body(h, wp, bp, out, blockIdx.x, threadIdx.x, sm2);
}

// ---------------- launcher ----------------

extern "C" void kernel_launch(void* const* d_in, const int* in_sizes, int n_in,
                              void* d_out, int out_size, void* d_ws, size_t ws_size,
                              hipStream_t stream) {
    const float* enc   = (const float*)d_in[0];
    const float* wih   = (const float*)d_in[1];
    const float* whh   = (const float*)d_in[2];
    const float* bih   = (const float*)d_in[3];
    const float* bhh   = (const float*)d_in[4];
    const float* wpred = (const float*)d_in[5];
    const float* bpred = (const float*)d_in[6];
    float* out = (float*)d_out;

    char* ws = (char*)d_ws;
    const size_t WH = (size_t)4 * H_SZ * H_SZ;
    const size_t BH = (size_t)B_SZ * H_SZ;
    bf16*  Wc   = (bf16*)ws;                 ws += WH * 2;
    bf16*  Wi   = (bf16*)ws;                 ws += WH * 2;
    bf16*  h0   = (bf16*)ws;                 ws += BH * 2;
    bf16*  h1   = (bf16*)ws;                 ws += BH * 2;
    float* cbuf = (float*)ws;                ws += BH * 4;
    bf16*  wp   = (bf16*)ws;                 ws += (size_t)A_SZ * H_SZ * 2;
    float* bias = (float*)ws;                ws += 4 * H_SZ * 4;

    prep_all<<<8336, 256, 0, stream>>>((const float4*)wih, (const float4*)whh, Wc, Wi,
                                       (const float4*)enc, h0,
                                       (const float4*)wpred, wp,
                                       bih, bhh, bias);

    bf16* hbuf[2] = {h0, h1};
    for (int s = 0; s < NSTEP; ++s) {
        const bf16* hin = hbuf[s & 1];
        bf16* hout      = hbuf[(s + 1) & 1];
        float* pout = (s == 0) ? nullptr : out + (size_t)(s - 1) * (B_SZ * A_SZ);
        lstm_fused<<<512, 512, 0, stream>>>(
            hin, (s == 0) ? Wi : Wc, bias, cbuf, hout, s == 0 ? 1 : 0,
            wp, bpred, pout);
    }
    // out[49] = h(50) @ wp^T + bp;  h(50) lives in hbuf[0] (step 49 wrote it)
    pred_tail<<<B_SZ / 16, 512, 0, stream>>>(
        hbuf[0], wp, bpred, out + (size_t)(NSTEP - 1) * (B_SZ * A_SZ));
}

// Round 12
// 2325.157 us; speedup vs baseline: 1.0487x; 1.0487x over previous
//
#include <hip/hip_runtime.h>
#include <hip/hip_bf16.h>
#include <stdint.h>

// Autoregressive LSTM decode, B=4096, H=1024, A=128, 50 steps.
// steps>=1: x==h  =>  gates = h @ (w_ih+w_hh)^T + bias.
// Fused launch: blocks 0-255 run the proven 256^2 8-phase gates GEMM + cell;
// blocks 256-511 compute pred for the PREVIOUS step (reads only hin, the
// gates input) in 16-row tiles, filling the gates completion tail.
// Final-step pred runs standalone; all prep fused into one launch.
// (Round-10 configuration, verbatim — session best 2329 us.)

#define B_SZ   4096
#define H_SZ   1024
#define A_SZ   128
#define NSTEP  50
#define NT     16      // gates K tiles of 64 (K = 1024)
#define NTP    8       // pred  K tiles of 128

using bf16 = __hip_bfloat16;
typedef __attribute__((ext_vector_type(8))) short bf16x8;   // 8 bf16 = 4 VGPR
typedef __attribute__((ext_vector_type(4))) float f32x4;    // MFMA C/D frag

__device__ __forceinline__ void gload_lds16(const void* g, void* l) {
    __builtin_amdgcn_global_load_lds(
        (const __attribute__((address_space(1))) unsigned int*)g,
        (__attribute__((address_space(3))) unsigned int*)l, 16, 0, 0);
}

#define FENCE() asm volatile("" ::: "memory")
#define BAR()   do { FENCE(); __builtin_amdgcn_s_barrier(); FENCE(); } while (0)
#define VMC6()  asm volatile("s_waitcnt vmcnt(6)" ::: "memory")
#define VMC5()  asm volatile("s_waitcnt vmcnt(5)" ::: "memory")
#define VMC4()  asm volatile("s_waitcnt vmcnt(4)" ::: "memory")
#define VMC0()  asm volatile("s_waitcnt vmcnt(0)" ::: "memory")
#define LGKM0() asm volatile("s_waitcnt lgkmcnt(0)" ::: "memory")

__device__ __forceinline__ float sigf(float x) {
    return 1.f / (1.f + __expf(-x));
}
__device__ __forceinline__ float tanh_(float x) {
    float e = __expf(-2.f * fabsf(x));
    float t = (1.f - e) / (1.f + e);
    return copysignf(t, x);
}

// ---------------- fused prep (one launch) ----------------
// blocks 0-4095: Wc/Wi from wih/whh; 4096-8191: enc cast; 8192-8319: wp cast;
// 8320-8335: bias add.

__global__ void prep_all(const float4* __restrict__ wih,
                         const float4* __restrict__ whh,
                         bf16* __restrict__ Wc, bf16* __restrict__ Wi,
                         const float4* __restrict__ enc, bf16* __restrict__ encb,
                         const float4* __restrict__ wpred, bf16* __restrict__ wpb,
                         const float* __restrict__ bih, const float* __restrict__ bhh,
                         float* __restrict__ bias) {
    const int b = blockIdx.x;
    if (b < 4096) {
        int i = b * 256 + threadIdx.x;
        float4 a = wih[i], c = whh[i];
        bf16 tc[4] = {__float2bfloat16(a.x + c.x), __float2bfloat16(a.y + c.y),
                      __float2bfloat16(a.z + c.z), __float2bfloat16(a.w + c.w)};
        bf16 ti[4] = {__float2bfloat16(a.x), __float2bfloat16(a.y),
                      __float2bfloat16(a.z), __float2bfloat16(a.w)};
        *(uint64_t*)(Wc + 4 * (size_t)i) = *(const uint64_t*)tc;
        *(uint64_t*)(Wi + 4 * (size_t)i) = *(const uint64_t*)ti;
    } else if (b < 8192) {
        int i = (b - 4096) * 256 + threadIdx.x;
        float4 a = enc[i];
        bf16 t[4] = {__float2bfloat16(a.x), __float2bfloat16(a.y),
                     __float2bfloat16(a.z), __float2bfloat16(a.w)};
        *(uint64_t*)(encb + 4 * (size_t)i) = *(const uint64_t*)t;
    } else if (b < 8320) {
        int i = (b - 8192) * 256 + threadIdx.x;
        float4 a = wpred[i];
        bf16 t[4] = {__float2bfloat16(a.x), __float2bfloat16(a.y),
                     __float2bfloat16(a.z), __float2bfloat16(a.w)};
        *(uint64_t*)(wpb + 4 * (size_t)i) = *(const uint64_t*)t;
    } else {
        int i = (b - 8320) * 256 + threadIdx.x;
        bias[i] = bih[i] + bhh[i];
    }
}

// ---------------- pred body: pout = h @ wp^T + bp for 16 rows ----------------
// 512 thr, 8 waves; block = 16 rows x 128 cols, BK=128 (NTP=8).
// LDS 72 KB double-buffered (aliased in caller's array). Waves 0-3 stage H+P
// (5 loads/tile), waves 4-7 stage P only (4); counted VMC5/VMC4 at boundaries.

__device__ __forceinline__ void pred_body(const bf16* __restrict__ h,
                                          const bf16* __restrict__ wp,
                                          const float* __restrict__ bp,
                                          float* __restrict__ pout,
                                          int pblk, int tid, bf16* sm) {
    bf16* const pH0 = sm;            // 16 x 128
    bf16* const pH1 = sm + 2048;
    bf16* const pP0 = sm + 4096;     // 128 x 128
    bf16* const pP1 = sm + 20480;

    const int w      = tid >> 6;
    const int lane   = tid & 63;
    const int lane15 = lane & 15;
    const int lhi    = lane >> 4;
    const int bm0    = pblk * 16;

    const int r   = tid >> 4;                               // stage row 0..31
    const int swb = ((tid & 15) * 16) ^ ((r & 7) << 4);     // pre-swizzled src
    const char* srcH = (const char*)h  + (size_t)(bm0 + (r & 15)) * 2048 + swb;
    const char* srcP = (const char*)wp + (size_t)r * 2048 + swb;

    int eoff[4];
#pragma unroll
    for (int kk = 0; kk < 4; ++kk)
        eoff[kk] = ((kk * 64 + lhi * 16) ^ ((lane15 & 7) << 4)) >> 1;

    f32x4 acc = {0.f, 0.f, 0.f, 0.f};

    auto STAGE = [&](int t) {
        bf16* dH = (t & 1) ? pH1 : pH0;
        bf16* dP = (t & 1) ? pP1 : pP0;
        if (w < 4)                                           // waves 0-3: H rows 0-15
            gload_lds16(srcH + (size_t)t * 256, dH + tid * 8);
#pragma unroll
        for (int q = 0; q < 4; ++q)                          // P rows r, r+32, r+64, r+96
            gload_lds16(srcP + (size_t)q * 65536 + (size_t)t * 256, dP + q * 4096 + tid * 8);
    };

    STAGE(0);
#pragma unroll
    for (int t = 0; t < NTP; ++t) {
        if (t + 1 < NTP) {
            STAGE(t + 1);
            if (w < 4) { VMC5(); } else { VMC4(); }
        } else {
            VMC0();
        }
        BAR();
        const bf16* Hd = (t & 1) ? pH1 : pH0;
        const bf16* Pd = (t & 1) ? pP1 : pP0;
#pragma unroll
        for (int kk = 0; kk < 4; ++kk) {
            bf16x8 a = *(const bf16x8*)(Hd + lane15 * 128 + eoff[kk]);
            bf16x8 b = *(const bf16x8*)(Pd + (w * 16 + lane15) * 128 + eoff[kk]);
            acc = __builtin_amdgcn_mfma_f32_16x16x32_bf16(a, b, acc, 0, 0, 0);
        }
        BAR();   // reads done before next STAGE overwrites the other buffer
    }

    const int col = w * 16 + lane15;
    const float bpv = bp[col];
#pragma unroll
    for (int rr = 0; rr < 4; ++rr)
        pout[(size_t)(bm0 + lhi * 4 + rr) * A_SZ + col] = acc[rr] + bpv;
}

// ---------------- fused gates GEMM + LSTM cell + tail-fill pred ----------------
// blocks 0-255: gates (round-2 proven structure, verbatim).
// blocks 256-511: pred for previous step (reads hin only) — fills the tail.

__global__ __launch_bounds__(512, 2)
void lstm_fused(const bf16* __restrict__ hin, const bf16* __restrict__ W,
                const float* __restrict__ bias, float* __restrict__ c,
                bf16* __restrict__ hout, int step0,
                const bf16* __restrict__ wp, const float* __restrict__ bp,
                float* __restrict__ pout) {
    __shared__ __align__(16) bf16 sm[65536];          // 128 KiB

    if (blockIdx.x >= 256) {
        if (pout) pred_body(hin, wp, bp, pout, blockIdx.x - 256, threadIdx.x, sm);
        return;
    }

    bf16* const lA0 = sm;
    bf16* const lA1 = sm + 16384;
    bf16* const lB0 = sm + 32768;
    bf16* const lB1 = sm + 49152;

    const int tid    = threadIdx.x;
    const int w      = tid >> 6;
    const int lane   = tid & 63;
    const int wr     = w >> 2;
    const int wc     = w & 3;
    const int lane15 = lane & 15;
    const int lhi    = lane >> 4;

    const int bid     = blockIdx.x;
    const int logical = (bid & 7) * 32 + (bid >> 3);   // bijective XCD swizzle
    const int bm0     = (logical >> 4) * 256;
    const int j0      = (logical & 15) * 64;

    const int scolb = ((tid & 7) * 16) ^ (((tid >> 3) & 7) << 4);
    const char* baseA = (const char*)hin + (size_t)(bm0 + (tid >> 3)) * 2048 + scolb;
    const char* baseB = (const char*)W   + (size_t)(j0  + (tid >> 3)) * 2048 + scolb;

    const int cs0 = ((     lhi * 16) ^ ((lane & 7) << 4)) >> 1;
    const int cs1 = ((64 + lhi * 16) ^ ((lane & 7) << 4)) >> 1;
    const int rA  = (wr * 128 + lane15) * 64;
    const int rB  = (wc * 16  + lane15) * 64;

    f32x4 acc[8][4];
    const f32x4 z = {0.f, 0.f, 0.f, 0.f};
#pragma unroll
    for (int m = 0; m < 8; ++m)
#pragma unroll
        for (int n = 0; n < 4; ++n) acc[m][n] = z;

    auto SGA = [&](int t, int h) {
        bf16* dst = ((t & 1) ? lA1 : lA0) + h * 8192 + w * 512;
        const char* g = baseA + (size_t)(h * 128) * 2048 + (size_t)t * 128;
        gload_lds16(g, dst);
        gload_lds16(g + (size_t)64 * 2048, dst + 4096);
    };
    auto SGB = [&](int t, int h) {
        bf16* dst = ((t & 1) ? lB1 : lB0) + h * 8192 + w * 512;
        const char* g = baseB + (size_t)(h * 2) * 2097152 + (size_t)t * 128;
        gload_lds16(g, dst);
        gload_lds16(g + 2097152, dst + 4096);
    };

    // prologue: 7 half-tile stages (14 gload_lds)
    SGB(0, 0); SGB(0, 1); SGA(0, 0); SGA(0, 1);
    SGB(1, 0); SGB(1, 1); SGA(1, 0);

    VMC6();
    BAR();

    for (int t = 0; t < NT; ++t) {
        const bf16* Ad = (t & 1) ? lA1 : lA0;
        const bf16* Bd = (t & 1) ? lB1 : lB0;
        bf16x8 av[4][2], bv[4][2];

        // phase 0: m0-3 x n0-1; stage A1(t+1)
#pragma unroll
        for (int m = 0; m < 4; ++m) {
            av[m][0] = *(const bf16x8*)(Ad + rA + m * 1024 + cs0);
            av[m][1] = *(const bf16x8*)(Ad + rA + m * 1024 + cs1);
        }
#pragma unroll
        for (int n = 0; n < 2; ++n) {
            bv[n][0] = *(const bf16x8*)(Bd + rB + n * 4096 + cs0);
            bv[n][1] = *(const bf16x8*)(Bd + rB + n * 4096 + cs1);
        }
        if (t + 1 < NT) SGA(t + 1, 1);
        BAR(); LGKM0();
        __builtin_amdgcn_s_setprio(1);
#pragma unroll
        for (int n = 0; n < 2; ++n)
#pragma unroll
            for (int m = 0; m < 4; ++m) {
                acc[m][n] = __builtin_amdgcn_mfma_f32_16x16x32_bf16(av[m][0], bv[n][0], acc[m][n], 0, 0, 0);
                acc[m][n] = __builtin_amdgcn_mfma_f32_16x16x32_bf16(av[m][1], bv[n][1], acc[m][n], 0, 0, 0);
            }
        __builtin_amdgcn_s_setprio(0);
        BAR();

        // phase 1: m0-3 x n2-3; stage B0(t+2)
#pragma unroll
        for (int n = 2; n < 4; ++n) {
            bv[n][0] = *(const bf16x8*)(Bd + rB + n * 4096 + cs0);
            bv[n][1] = *(const bf16x8*)(Bd + rB + n * 4096 + cs1);
        }
        if (t + 2 < NT) SGB(t + 2, 0);
        BAR(); LGKM0();
        __builtin_amdgcn_s_setprio(1);
#pragma unroll
        for (int n = 2; n < 4; ++n)
#pragma unroll
            for (int m = 0; m < 4; ++m) {
                acc[m][n] = __builtin_amdgcn_mfma_f32_16x16x32_bf16(av[m][0], bv[n][0], acc[m][n], 0, 0, 0);
                acc[m][n] = __builtin_amdgcn_mfma_f32_16x16x32_bf16(av[m][1], bv[n][1], acc[m][n], 0, 0, 0);
            }
        __builtin_amdgcn_s_setprio(0);
        BAR();

        // phase 2: m4-7 x n0-1; stage B1(t+2)
#pragma unroll
        for (int m = 0; m < 4; ++m) {
            av[m][0] = *(const bf16x8*)(Ad + rA + (m + 4) * 1024 + cs0);
            av[m][1] = *(const bf16x8*)(Ad + rA + (m + 4) * 1024 + cs1);
        }
        if (t + 2 < NT) SGB(t + 2, 1);
        BAR(); LGKM0();
        __builtin_amdgcn_s_setprio(1);
#pragma unroll
        for (int n = 0; n < 2; ++n)
#pragma unroll
            for (int m = 0; m < 4; ++m) {
                acc[m + 4][n] = __builtin_amdgcn_mfma_f32_16x16x32_bf16(av[m][0], bv[n][0], acc[m + 4][n], 0, 0, 0);
                acc[m + 4][n] = __builtin_amdgcn_mfma_f32_16x16x32_bf16(av[m][1], bv[n][1], acc[m + 4][n], 0, 0, 0);
            }
        __builtin_amdgcn_s_setprio(0);
        BAR();

        // phase 3: m4-7 x n2-3; stage A0(t+2)
        if (t + 2 < NT) SGA(t + 2, 0);
        BAR(); LGKM0();
        __builtin_amdgcn_s_setprio(1);
#pragma unroll
        for (int n = 2; n < 4; ++n)
#pragma unroll
            for (int m = 0; m < 4; ++m) {
                acc[m + 4][n] = __builtin_amdgcn_mfma_f32_16x16x32_bf16(av[m][0], bv[n][0], acc[m + 4][n], 0, 0, 0);
                acc[m + 4][n] = __builtin_amdgcn_mfma_f32_16x16x32_bf16(av[m][1], bv[n][1], acc[m + 4][n], 0, 0, 0);
            }
        __builtin_amdgcn_s_setprio(0);
        if (t < NT - 1) {
            if (t == NT - 2) { VMC0(); } else { VMC6(); }
        }
        BAR();
    }

    // ---- fused LSTM cell epilogue (i/f/g/o lane-local: n-frag == gate)
    const int jc = j0 + wc * 16 + lane15;
    const float bi  = bias[jc];
    const float bff = bias[H_SZ + jc];
    const float bg  = bias[2 * H_SZ + jc];
    const float bo  = bias[3 * H_SZ + jc];
#pragma unroll
    for (int m = 0; m < 8; ++m) {
#pragma unroll
        for (int r = 0; r < 4; ++r) {
            int row = bm0 + wr * 128 + m * 16 + lhi * 4 + r;
            size_t idx = (size_t)row * H_SZ + jc;
            float iv = acc[m][0][r] + bi;
            float fv = acc[m][1][r] + bff;
            float gv = acc[m][2][r] + bg;
            float ov = acc[m][3][r] + bo;
            float cp = step0 ? 0.f : c[idx];
            float cn = sigf(fv) * cp + sigf(iv) * tanh_(gv);
            float hn = sigf(ov) * tanh_(cn);
            c[idx] = cn;
            hout[idx] = __float2bfloat16(hn);
        }
    }
}

// ---------------- standalone pred for the final step ----------------

__global__ __launch_bounds__(512)
void pred_tail(const bf16* __restrict__ h, const bf16* __restrict__ wp,
               const float* __restrict__ bp, float* __restrict__ out) {
    __shared__ __align__(16) bf16 sm2[36864];     // 72 KiB
    pred_body(h, wp, bp, out, blockIdx.x, threadIdx.x, sm2);
}

// ---------------- launcher ----------------

extern "C" void kernel_launch(void* const* d_in, const int* in_sizes, int n_in,
                              void* d_out, int out_size, void* d_ws, size_t ws_size,
                              hipStream_t stream) {
    const float* enc   = (const float*)d_in[0];
    const float* wih   = (const float*)d_in[1];
    const float* whh   = (const float*)d_in[2];
    const float* bih   = (const float*)d_in[3];
    const float* bhh   = (const float*)d_in[4];
    const float* wpred = (const float*)d_in[5];
    const float* bpred = (const float*)d_in[6];
    float* out = (float*)d_out;

    char* ws = (char*)d_ws;
    const size_t WH = (size_t)4 * H_SZ * H_SZ;
    const size_t BH = (size_t)B_SZ * H_SZ;
    bf16*  Wc   = (bf16*)ws;                 ws += WH * 2;
    bf16*  Wi   = (bf16*)ws;                 ws += WH * 2;
    bf16*  h0   = (bf16*)ws;                 ws += BH * 2;
    bf16*  h1   = (bf16*)ws;                 ws += BH * 2;
    float* cbuf = (float*)ws;                ws += BH * 4;
    bf16*  wp   = (bf16*)ws;                 ws += (size_t)A_SZ * H_SZ * 2;
    float* bias = (float*)ws;                ws += 4 * H_SZ * 4;

    prep_all<<<8336, 256, 0, stream>>>((const float4*)wih, (const float4*)whh, Wc, Wi,
                                       (const float4*)enc, h0,
                                       (const float4*)wpred, wp,
                                       bih, bhh, bias);

    bf16* hbuf[2] = {h0, h1};
    for (int s = 0; s < NSTEP; ++s) {
        const bf16* hin = hbuf[s & 1];
        bf16* hout      = hbuf[(s + 1) & 1];
        float* pout = (s == 0) ? nullptr : out + (size_t)(s - 1) * (B_SZ * A_SZ);
        lstm_fused<<<512, 512, 0, stream>>>(
            hin, (s == 0) ? Wi : Wc, bias, cbuf, hout, s == 0 ? 1 : 0,
            wp, bpred, pout);
    }
    // out[49] = h(50) @ wp^T + bp;  h(50) lives in hbuf[0] (step 49 wrote it)
    pred_tail<<<B_SZ / 16, 512, 0, stream>>>(
        hbuf[0], wp, bpred, out + (size_t)(NSTEP - 1) * (B_SZ * A_SZ));
}